// Round 4
// baseline (339.518 us; speedup 1.0000x reference)
//
#include <hip/hip_runtime.h>
#include <hip/hip_bf16.h>

#define SEQ   4096
#define EMB   512
#define NH    8
#define DH    64
#define QBLK  64
#define KVBLK 64

typedef __attribute__((ext_vector_type(8))) short short8;
typedef __attribute__((ext_vector_type(4))) short short4v;
typedef __attribute__((ext_vector_type(4))) float floatx4;

__device__ __forceinline__ short bf16of(float f) {
    return __builtin_bit_cast(short, __float2bfloat16(f));
}

// Flash-attention forward. One block = 64 q rows of one (b,h); 4 waves, each
// wave owns 16 q rows. K tile row-major, V tile transposed, both bf16 in LDS
// with XOR swizzle (byte ^= (row&7)<<4  ==  elem ^= (row&7)<<3).
__global__ __launch_bounds__(256) void mha_fwd(
    const float* __restrict__ q, const float* __restrict__ k,
    const float* __restrict__ v, float* __restrict__ out)
{
    __shared__ __align__(16) short lK[KVBLK * DH];      // [j][d] swizzled
    __shared__ __align__(16) short lV[DH * KVBLK];      // [d][j] swizzled (V^T)
    __shared__ __align__(16) short lP[4 * 16 * KVBLK];  // per-wave [i][j] swizzled

    const int bid  = blockIdx.x;
    const int bh   = bid >> 6;        // 16 (b,h) pairs
    const int qt   = bid & 63;        // 64 q-tiles
    const int b    = bh >> 3, h = bh & 7;
    const int tid  = threadIdx.x;
    const int wave = tid >> 6, lane = tid & 63;
    const int lo   = lane & 15, hi = lane >> 4;

    const size_t base = (size_t)b * SEQ * EMB + h * DH;  // + n*EMB + d

    // ---- Q fragments, held in registers for the whole kernel ----
    // A-frag layout: row = lane&15, k = (lane>>4)*8 + jj (8 contiguous d)
    short8 qfrag[2];
    {
        const int qrow = qt * QBLK + wave * 16 + lo;
        const float* qp = q + base + (size_t)qrow * EMB;
        #pragma unroll
        for (int kk = 0; kk < 2; ++kk) {
            const int d0 = kk * 32 + hi * 8;
            floatx4 f0 = *(const floatx4*)(qp + d0);
            floatx4 f1 = *(const floatx4*)(qp + d0 + 4);
            short8 t;
            #pragma unroll
            for (int j = 0; j < 4; ++j) { t[j] = bf16of(f0[j]); t[4 + j] = bf16of(f1[j]); }
            qfrag[kk] = t;
        }
    }

    floatx4 o[4];                      // O acc: row = hi*4+r, col = dt*16+lo
    float m[4], l[4];
    #pragma unroll
    for (int dt = 0; dt < 4; ++dt) o[dt] = (floatx4){0.f, 0.f, 0.f, 0.f};
    #pragma unroll
    for (int r = 0; r < 4; ++r) { m[r] = -__builtin_inff(); l[r] = 0.f; }

    const float sl2e = 0.125f * 1.44269504088896f;  // scale * log2(e)

    for (int kv0 = 0; kv0 < SEQ; kv0 += KVBLK) {
        __syncthreads();  // previous iteration done reading lK/lV

        // ---- stage K tile (row-major, swizzled), coalesced float4 loads ----
        #pragma unroll
        for (int w = 0; w < 4; ++w) {
            const int idx = w * 256 + tid;           // float4 index in 64x64
            const int row = idx >> 4;
            const int col = (idx & 15) * 4;
            floatx4 f = *(const floatx4*)(k + base + (size_t)(kv0 + row) * EMB + col);
            short4v hs;
            #pragma unroll
            for (int j = 0; j < 4; ++j) hs[j] = bf16of(f[j]);
            *(short4v*)&lK[(row * 64 + col) ^ ((row & 7) << 3)] = hs;
        }
        // ---- stage V transposed: lV[d][j] = V[j][d] ----
        {
            const int d = tid & 63, jg = tid >> 6;
            short vals[16];
            #pragma unroll
            for (int i = 0; i < 16; ++i)
                vals[i] = bf16of(v[base + (size_t)(kv0 + jg * 16 + i) * EMB + d]);
            short8 va, vb;
            #pragma unroll
            for (int i = 0; i < 8; ++i) { va[i] = vals[i]; vb[i] = vals[8 + i]; }
            *(short8*)&lV[(d * 64 + jg * 16) ^ ((d & 7) << 3)] = va;
            *(short8*)&lV[(d * 64 + jg * 16 + 8) ^ ((d & 7) << 3)] = vb;
        }
        __syncthreads();

        // ---- S = Q K^T : 4 j-tiles of 16, C layout row=hi*4+r col=lo ----
        floatx4 s[4];
        #pragma unroll
        for (int jt = 0; jt < 4; ++jt) s[jt] = (floatx4){0.f, 0.f, 0.f, 0.f};
        #pragma unroll
        for (int jt = 0; jt < 4; ++jt) {
            const int j = jt * 16 + lo;
            #pragma unroll
            for (int kk = 0; kk < 2; ++kk) {
                short8 kf = *(const short8*)&lK[(j * 64 + kk * 32 + hi * 8) ^ ((j & 7) << 3)];
                s[jt] = __builtin_amdgcn_mfma_f32_16x16x32_bf16(qfrag[kk], kf, s[jt], 0, 0, 0);
            }
        }
        #pragma unroll
        for (int jt = 0; jt < 4; ++jt) s[jt] *= sl2e;   // log2-domain logits

        // ---- online softmax (row reduce across 16-lane groups) ----
        float p[4][4];
        #pragma unroll
        for (int r = 0; r < 4; ++r) {
            float mx = fmaxf(fmaxf(s[0][r], s[1][r]), fmaxf(s[2][r], s[3][r]));
            #pragma unroll
            for (int msk = 1; msk <= 8; msk <<= 1) mx = fmaxf(mx, __shfl_xor(mx, msk, 64));
            const float mnew  = fmaxf(m[r], mx);
            const float alpha = __builtin_amdgcn_exp2f(m[r] - mnew);
            float rs = 0.f;
            #pragma unroll
            for (int jt = 0; jt < 4; ++jt) {
                p[jt][r] = __builtin_amdgcn_exp2f(s[jt][r] - mnew);
                rs += p[jt][r];
            }
            #pragma unroll
            for (int msk = 1; msk <= 8; msk <<= 1) rs += __shfl_xor(rs, msk, 64);
            l[r] = l[r] * alpha + rs;
            m[r] = mnew;
            #pragma unroll
            for (int dt = 0; dt < 4; ++dt) o[dt][r] *= alpha;
        }

        // ---- P -> LDS (bf16, swizzled, per-wave region) ----
        #pragma unroll
        for (int jt = 0; jt < 4; ++jt)
            #pragma unroll
            for (int r = 0; r < 4; ++r) {
                const int i = hi * 4 + r, j = jt * 16 + lo;
                lP[wave * 1024 + ((i * 64 + j) ^ ((i & 7) << 3))] = bf16of(p[jt][r]);
            }
        __syncthreads();

        // ---- O += P V : A-frag from lP, B-frag from lV (contiguous j) ----
        short8 pf[2];
        #pragma unroll
        for (int kk = 0; kk < 2; ++kk)
            pf[kk] = *(const short8*)&lP[wave * 1024 +
                       ((lo * 64 + kk * 32 + hi * 8) ^ ((lo & 7) << 3))];
        #pragma unroll
        for (int dt = 0; dt < 4; ++dt) {
            const int d = dt * 16 + lo;
            #pragma unroll
            for (int kk = 0; kk < 2; ++kk) {
                short8 vf = *(const short8*)&lV[(d * 64 + kk * 32 + hi * 8) ^ ((d & 7) << 3)];
                o[dt] = __builtin_amdgcn_mfma_f32_16x16x32_bf16(pf[kk], vf, o[dt], 0, 0, 0);
            }
        }
    }

    // ---- epilogue: normalize and store fp32 ----
    const int orow = qt * QBLK + wave * 16 + hi * 4;
    #pragma unroll
    for (int r = 0; r < 4; ++r) {
        const float inv = 1.f / l[r];
        float* op = out + (size_t)b * SEQ * EMB + (size_t)(orow + r) * EMB + h * DH + lo;
        #pragma unroll
        for (int dt = 0; dt < 4; ++dt) op[dt * 16] = o[dt][r] * inv;
    }
}

extern "C" void kernel_launch(void* const* d_in, const int* in_sizes, int n_in,
                              void* d_out, int out_size, void* d_ws, size_t ws_size,
                              hipStream_t stream) {
    const float* q = (const float*)d_in[0];
    const float* k = (const float*)d_in[1];
    const float* v = (const float*)d_in[2];
    float* out = (float*)d_out;
    dim3 grid(16 * 64);   // (b,h) major, q-tile minor
    dim3 block(256);
    mha_fwd<<<grid, block, 0, stream>>>(q, k, v, out);
}

// Round 5
// 201.992 us; speedup vs baseline: 1.6808x; 1.6808x over previous
//
#include <hip/hip_runtime.h>
#include <hip/hip_bf16.h>

#define SEQ   4096
#define EMB   512
#define NH    8
#define DH    64
#define KVBLK 64
#define WQ    32
#define NWAVE 4
#define QBLK  (WQ*NWAVE)   // 128 q rows per block

typedef __attribute__((ext_vector_type(8)))  short short8;
typedef __attribute__((ext_vector_type(4)))  short short4v;
typedef __attribute__((ext_vector_type(4)))  float floatx4;
typedef __attribute__((ext_vector_type(16))) float f32x16;
typedef __attribute__((ext_vector_type(4)))  unsigned int uint4v;

__device__ __forceinline__ short bf16of(float f) {
    return __builtin_bit_cast(short, __float2bfloat16(f));
}
__device__ __forceinline__ unsigned int packbf(float a, float b) {
    unsigned int x = (unsigned short)bf16of(a);
    unsigned int y = (unsigned short)bf16of(b);
    return x | (y << 16);
}

// ---------- prep: K [b,n,h*d] fp32 -> Kb [bh,n,d] bf16 ----------
__global__ __launch_bounds__(256) void prep_k(const float* __restrict__ k,
                                              short* __restrict__ kb) {
    int gid = blockIdx.x * 256 + threadIdx.x;      // one 8-elem chunk
    int d8 = gid & 7, n = (gid >> 3) & (SEQ - 1), bh = gid >> 15;
    int b = bh >> 3, h = bh & 7;
    const float* src = k + ((size_t)(b * SEQ + n)) * EMB + h * DH + d8 * 8;
    floatx4 f0 = *(const floatx4*)src, f1 = *(const floatx4*)(src + 4);
    short8 o;
    #pragma unroll
    for (int j = 0; j < 4; ++j) { o[j] = bf16of(f0[j]); o[4 + j] = bf16of(f1[j]); }
    *(short8*)(kb + (size_t)gid * 8) = o;
}

// ---------- prep: V [b,n,h*d] fp32 -> Vt [bh,d,n] bf16 (transpose via LDS) ----------
__global__ __launch_bounds__(256) void prep_v(const float* __restrict__ v,
                                              short* __restrict__ vt) {
    __shared__ short t[64][72];                    // pad 72 keeps short8 rows 16B-aligned
    int bid = blockIdx.x;                          // bh*64 + ntile
    int bh = bid >> 6, nt = bid & 63;
    int b = bh >> 3, h = bh & 7;
    int tid = threadIdx.x;
    int nl = tid >> 2, d0 = (tid & 3) * 16;
    const float* src = v + ((size_t)(b * SEQ + nt * 64 + nl)) * EMB + h * DH + d0;
    #pragma unroll
    for (int c = 0; c < 4; ++c) {
        floatx4 f = *(const floatx4*)(src + c * 4);
        #pragma unroll
        for (int j = 0; j < 4; ++j) t[d0 + c * 4 + j][nl] = bf16of(f[j]);
    }
    __syncthreads();
    int dl = tid >> 2, n0 = (tid & 3) * 16;
    short8 a  = *(const short8*)&t[dl][n0];
    short8 b2 = *(const short8*)&t[dl][n0 + 8];
    short* dst = vt + ((size_t)bh * DH + dl) * SEQ + nt * 64 + n0;
    *(short8*)dst       = a;
    *(short8*)(dst + 8) = b2;
}

// ---------- main: swapped-QK^T flash attention, 32x32x16 MFMA ----------
// Wave owns 32 q rows (one per lane-col). S^T = K·Q^T so lane q=lane&31 holds
// its full P row in regs; O^T = Vt·P^T keeps q on the MFMA column so m/l/O
// rescale is scalar per lane. P^T B-frags built via pack + shfl_xor(32).
__global__ __launch_bounds__(256) void mha_fwd2(
    const float* __restrict__ q, const short* __restrict__ kb,
    const short* __restrict__ vt, float* __restrict__ out)
{
    __shared__ __align__(16) short lK[64 * 64];    // [j][d] swizzled
    __shared__ __align__(16) short lV[64 * 64];    // [d][j] swizzled

    const int bid = blockIdx.x;
    const int bh = bid >> 5, qt = bid & 31;        // 16 bh x 32 q-tiles
    const int b = bh >> 3, h = bh & 7;
    const int tid = threadIdx.x;
    const int wave = tid >> 6, lane = tid & 63;
    const int ql = lane & 31, hf = lane >> 5;

    const short* kbb = kb + (size_t)bh * SEQ * DH;
    const short* vtb = vt + (size_t)bh * DH * SEQ;

    // Q B-frags: lane holds Q[qg][d=16ks+8hf .. +7] * scale*log2e
    const int qg = qt * QBLK + wave * WQ + ql;
    const float sl2e = 0.125f * 1.44269504088896f;
    short8 qf[4];
    {
        const float* qp = q + ((size_t)b * SEQ + qg) * EMB + h * DH;
        #pragma unroll
        for (int ks = 0; ks < 4; ++ks) {
            const int d0 = ks * 16 + hf * 8;
            floatx4 f0 = *(const floatx4*)(qp + d0);
            floatx4 f1 = *(const floatx4*)(qp + d0 + 4);
            short8 t;
            #pragma unroll
            for (int j = 0; j < 4; ++j) {
                t[j]     = bf16of(f0[j] * sl2e);
                t[4 + j] = bf16of(f1[j] * sl2e);
            }
            qf[ks] = t;
        }
    }

    f32x16 o0, o1;
    #pragma unroll
    for (int i = 0; i < 16; ++i) { o0[i] = 0.f; o1[i] = 0.f; }
    float mrow = -__builtin_inff(), lrow = 0.f;

    // staging: 2 short8 chunks per thread per tile (64x64 bf16 = 8KB)
    const int r0 = tid >> 3,          col0 = (tid & 7) * 8;
    const int r1 = (256 + tid) >> 3,  col1 = (tid & 7) * 8;

    short8 rk0 = *(const short8*)(kbb + (size_t)r0 * DH + col0);
    short8 rk1 = *(const short8*)(kbb + (size_t)r1 * DH + col1);
    short8 rv0 = *(const short8*)(vtb + (size_t)r0 * SEQ + col0);
    short8 rv1 = *(const short8*)(vtb + (size_t)r1 * SEQ + col1);

    for (int kv0 = 0; kv0 < SEQ; kv0 += KVBLK) {
        __syncthreads();   // prev iter done reading LDS
        *(short8*)&lK[(r0 * 64 + col0) ^ ((r0 & 7) << 3)] = rk0;
        *(short8*)&lK[(r1 * 64 + col1) ^ ((r1 & 7) << 3)] = rk1;
        *(short8*)&lV[(r0 * 64 + col0) ^ ((r0 & 7) << 3)] = rv0;
        *(short8*)&lV[(r1 * 64 + col1) ^ ((r1 & 7) << 3)] = rv1;
        __syncthreads();
        if (kv0 + KVBLK < SEQ) {   // prefetch next tile under compute
            const int nx = kv0 + KVBLK;
            rk0 = *(const short8*)(kbb + (size_t)(nx + r0) * DH + col0);
            rk1 = *(const short8*)(kbb + (size_t)(nx + r1) * DH + col1);
            rv0 = *(const short8*)(vtb + (size_t)r0 * SEQ + nx + col0);
            rv1 = *(const short8*)(vtb + (size_t)r1 * SEQ + nx + col1);
        }

        // ---- S^T = K·Q^T : lane holds S[j][q=ql], j over reg pattern ----
        f32x16 s0, s1;
        #pragma unroll
        for (int i = 0; i < 16; ++i) { s0[i] = 0.f; s1[i] = 0.f; }
        #pragma unroll
        for (int ks = 0; ks < 4; ++ks) {
            const int cb = ks * 16 + hf * 8;
            short8 ka = *(const short8*)&lK[(ql * 64 + cb) ^ ((ql & 7) << 3)];
            short8 kc = *(const short8*)&lK[((ql + 32) * 64 + cb) ^ ((ql & 7) << 3)];
            s0 = __builtin_amdgcn_mfma_f32_32x32x16_bf16(ka, qf[ks], s0, 0, 0, 0);
            s1 = __builtin_amdgcn_mfma_f32_32x32x16_bf16(kc, qf[ks], s1, 0, 0, 0);
        }

        // ---- online softmax, lane-local (q = ql), log2 domain ----
        float pmax = s0[0];
        #pragma unroll
        for (int r = 1; r < 16; ++r) pmax = fmaxf(pmax, s0[r]);
        #pragma unroll
        for (int r = 0; r < 16; ++r) pmax = fmaxf(pmax, s1[r]);
        pmax = fmaxf(pmax, __shfl_xor(pmax, 32, 64));
        if (__any(pmax > mrow + 8.f)) {            // defer-max (T13)
            const float mn = fmaxf(mrow, pmax);
            const float al = __builtin_amdgcn_exp2f(mrow - mn);
            lrow *= al;  o0 *= al;  o1 *= al;
            mrow = mn;
        }
        float rs = 0.f;
        #pragma unroll
        for (int r = 0; r < 16; ++r) { s0[r] = __builtin_amdgcn_exp2f(s0[r] - mrow); rs += s0[r]; }
        #pragma unroll
        for (int r = 0; r < 16; ++r) { s1[r] = __builtin_amdgcn_exp2f(s1[r] - mrow); rs += s1[r]; }
        rs += __shfl_xor(rs, 32, 64);
        lrow += rs;

        // ---- pack P to bf16 words: w[g] = quad j=8g+4hf+c, c=0..3 ----
        unsigned int w[8][2];
        #pragma unroll
        for (int g = 0; g < 4; ++g) {
            w[g][0]     = packbf(s0[4 * g],     s0[4 * g + 1]);
            w[g][1]     = packbf(s0[4 * g + 2], s0[4 * g + 3]);
            w[4 + g][0] = packbf(s1[4 * g],     s1[4 * g + 1]);
            w[4 + g][1] = packbf(s1[4 * g + 2], s1[4 * g + 3]);
        }

        // ---- O^T += Vt·P^T : per ks, B-frag j-block [16ks+8hf, +7] ----
        #pragma unroll
        for (int ks = 0; ks < 4; ++ks) {
            // local quad g=2ks+hf; send quad g=2ks+(1-hf) to the other half
            unsigned int wl0 = hf ? w[2 * ks + 1][0] : w[2 * ks][0];
            unsigned int wl1 = hf ? w[2 * ks + 1][1] : w[2 * ks][1];
            unsigned int ws0 = hf ? w[2 * ks][0]     : w[2 * ks + 1][0];
            unsigned int ws1 = hf ? w[2 * ks][1]     : w[2 * ks + 1][1];
            unsigned int x0 = __shfl_xor(ws0, 32, 64);
            unsigned int x1 = __shfl_xor(ws1, 32, 64);
            uint4v pw;
            pw.x = hf ? x0 : wl0;   // jj 0..1
            pw.y = hf ? x1 : wl1;   // jj 2..3
            pw.z = hf ? wl0 : x0;   // jj 4..5
            pw.w = hf ? wl1 : x1;   // jj 6..7
            short8 pf = __builtin_bit_cast(short8, pw);
            const int cb = ks * 16 + hf * 8;
            short8 va = *(const short8*)&lV[(ql * 64 + cb) ^ ((ql & 7) << 3)];
            short8 vb = *(const short8*)&lV[((ql + 32) * 64 + cb) ^ ((ql & 7) << 3)];
            o0 = __builtin_amdgcn_mfma_f32_32x32x16_bf16(va, pf, o0, 0, 0, 0);
            o1 = __builtin_amdgcn_mfma_f32_32x32x16_bf16(vb, pf, o1, 0, 0, 0);
        }
    }

    // ---- epilogue: O^T rows d = (r&3)+8(r>>2)+4hf (+32), col q = ql ----
    const float inv = 1.f / lrow;
    float* op = out + ((size_t)b * SEQ + qg) * EMB + h * DH;
    #pragma unroll
    for (int r = 0; r < 16; ++r) {
        const int d = (r & 3) + 8 * (r >> 2) + 4 * hf;
        op[d]      = o0[r] * inv;
        op[d + 32] = o1[r] * inv;
    }
}

// ---------- fallback (round-4 verified kernel), used if ws too small ----------
__global__ __launch_bounds__(256) void mha_fwd(
    const float* __restrict__ q, const float* __restrict__ k,
    const float* __restrict__ v, float* __restrict__ out)
{
    __shared__ __align__(16) short lK[KVBLK * DH];
    __shared__ __align__(16) short lV[DH * KVBLK];
    __shared__ __align__(16) short lP[4 * 16 * KVBLK];

    const int bid  = blockIdx.x;
    const int bh   = bid >> 6;
    const int qt   = bid & 63;
    const int b    = bh >> 3, h = bh & 7;
    const int tid  = threadIdx.x;
    const int wave = tid >> 6, lane = tid & 63;
    const int lo   = lane & 15, hi = lane >> 4;
    const size_t base = (size_t)b * SEQ * EMB + h * DH;

    short8 qfrag[2];
    {
        const int qrow = qt * 64 + wave * 16 + lo;
        const float* qp = q + base + (size_t)qrow * EMB;
        #pragma unroll
        for (int kk = 0; kk < 2; ++kk) {
            const int d0 = kk * 32 + hi * 8;
            floatx4 f0 = *(const floatx4*)(qp + d0);
            floatx4 f1 = *(const floatx4*)(qp + d0 + 4);
            short8 t;
            #pragma unroll
            for (int j = 0; j < 4; ++j) { t[j] = bf16of(f0[j]); t[4 + j] = bf16of(f1[j]); }
            qfrag[kk] = t;
        }
    }
    floatx4 o[4];
    float m[4], l[4];
    #pragma unroll
    for (int dt = 0; dt < 4; ++dt) o[dt] = (floatx4){0.f, 0.f, 0.f, 0.f};
    #pragma unroll
    for (int r = 0; r < 4; ++r) { m[r] = -__builtin_inff(); l[r] = 0.f; }
    const float sl2e = 0.125f * 1.44269504088896f;

    for (int kv0 = 0; kv0 < SEQ; kv0 += KVBLK) {
        __syncthreads();
        #pragma unroll
        for (int w = 0; w < 4; ++w) {
            const int idx = w * 256 + tid;
            const int row = idx >> 4;
            const int col = (idx & 15) * 4;
            floatx4 f = *(const floatx4*)(k + base + (size_t)(kv0 + row) * EMB + col);
            short4v hs;
            #pragma unroll
            for (int j = 0; j < 4; ++j) hs[j] = bf16of(f[j]);
            *(short4v*)&lK[(row * 64 + col) ^ ((row & 7) << 3)] = hs;
        }
        {
            const int d = tid & 63, jg = tid >> 6;
            short vals[16];
            #pragma unroll
            for (int i = 0; i < 16; ++i)
                vals[i] = bf16of(v[base + (size_t)(kv0 + jg * 16 + i) * EMB + d]);
            short8 va, vb;
            #pragma unroll
            for (int i = 0; i < 8; ++i) { va[i] = vals[i]; vb[i] = vals[8 + i]; }
            *(short8*)&lV[(d * 64 + jg * 16) ^ ((d & 7) << 3)] = va;
            *(short8*)&lV[(d * 64 + jg * 16 + 8) ^ ((d & 7) << 3)] = vb;
        }
        __syncthreads();

        floatx4 s[4];
        #pragma unroll
        for (int jt = 0; jt < 4; ++jt) s[jt] = (floatx4){0.f, 0.f, 0.f, 0.f};
        #pragma unroll
        for (int jt = 0; jt < 4; ++jt) {
            const int j = jt * 16 + lo;
            #pragma unroll
            for (int kk = 0; kk < 2; ++kk) {
                short8 kf = *(const short8*)&lK[(j * 64 + kk * 32 + hi * 8) ^ ((j & 7) << 3)];
                s[jt] = __builtin_amdgcn_mfma_f32_16x16x32_bf16(qfrag[kk], kf, s[jt], 0, 0, 0);
            }
        }
        #pragma unroll
        for (int jt = 0; jt < 4; ++jt) s[jt] *= sl2e;

        float p[4][4];
        #pragma unroll
        for (int r = 0; r < 4; ++r) {
            float mx = fmaxf(fmaxf(s[0][r], s[1][r]), fmaxf(s[2][r], s[3][r]));
            #pragma unroll
            for (int msk = 1; msk <= 8; msk <<= 1) mx = fmaxf(mx, __shfl_xor(mx, msk, 64));
            const float mnew  = fmaxf(m[r], mx);
            const float alpha = __builtin_amdgcn_exp2f(m[r] - mnew);
            float rs = 0.f;
            #pragma unroll
            for (int jt = 0; jt < 4; ++jt) {
                p[jt][r] = __builtin_amdgcn_exp2f(s[jt][r] - mnew);
                rs += p[jt][r];
            }
            #pragma unroll
            for (int msk = 1; msk <= 8; msk <<= 1) rs += __shfl_xor(rs, msk, 64);
            l[r] = l[r] * alpha + rs;
            m[r] = mnew;
            #pragma unroll
            for (int dt = 0; dt < 4; ++dt) o[dt][r] *= alpha;
        }
        #pragma unroll
        for (int jt = 0; jt < 4; ++jt)
            #pragma unroll
            for (int r = 0; r < 4; ++r) {
                const int i = hi * 4 + r, j = jt * 16 + lo;
                lP[wave * 1024 + ((i * 64 + j) ^ ((i & 7) << 3))] = bf16of(p[jt][r]);
            }
        __syncthreads();

        short8 pf[2];
        #pragma unroll
        for (int kk = 0; kk < 2; ++kk)
            pf[kk] = *(const short8*)&lP[wave * 1024 +
                       ((lo * 64 + kk * 32 + hi * 8) ^ ((lo & 7) << 3))];
        #pragma unroll
        for (int dt = 0; dt < 4; ++dt) {
            const int d = dt * 16 + lo;
            #pragma unroll
            for (int kk = 0; kk < 2; ++kk) {
                short8 vf = *(const short8*)&lV[(d * 64 + kk * 32 + hi * 8) ^ ((d & 7) << 3)];
                o[dt] = __builtin_amdgcn_mfma_f32_16x16x32_bf16(pf[kk], vf, o[dt], 0, 0, 0);
            }
        }
    }
    const int orow = qt * 64 + wave * 16 + hi * 4;
    #pragma unroll
    for (int r = 0; r < 4; ++r) {
        const float inv = 1.f / l[r];
        float* op = out + (size_t)b * SEQ * EMB + (size_t)(orow + r) * EMB + h * DH + lo;
        #pragma unroll
        for (int dt = 0; dt < 4; ++dt) op[dt * 16] = o[dt][r] * inv;
    }
}

extern "C" void kernel_launch(void* const* d_in, const int* in_sizes, int n_in,
                              void* d_out, int out_size, void* d_ws, size_t ws_size,
                              hipStream_t stream) {
    const float* q = (const float*)d_in[0];
    const float* k = (const float*)d_in[1];
    const float* v = (const float*)d_in[2];
    float* out = (float*)d_out;

    const size_t elems = (size_t)2 * NH * SEQ * DH;      // 4.19M bf16 per tensor
    const size_t need  = 2 * elems * sizeof(short);      // Kb + Vt = 16.8 MB

    if (ws_size >= need) {
        short* kbuf = (short*)d_ws;
        short* vbuf = kbuf + elems;
        prep_k<<<dim3(2048), dim3(256), 0, stream>>>(k, kbuf);
        prep_v<<<dim3(1024), dim3(256), 0, stream>>>(v, vbuf);
        mha_fwd2<<<dim3(512), dim3(256), 0, stream>>>(q, kbuf, vbuf, out);
    } else {
        mha_fwd<<<dim3(1024), dim3(256), 0, stream>>>(q, k, v, out);
    }
}